// Round 1
// baseline (667.843 us; speedup 1.0000x reference)
//
#include <hip/hip_runtime.h>

#define B_ 16
#define T_ 4096
#define HKV_ 8
#define HD_ 128
#define DM_ 4096
#define HQ_ 32
#define G_ 4
#define CHUNK_ 64
#define TOPK_ 16
#define WINDOW_ 512
#define NC_ 64
#define EPS_ 1e-6f

#define SPLITK 32
#define KCH (DM_ / SPLITK)   // 128

// ---------------- GEMM stage 1: partials[ky][b][n] = sum_{k in slice} A[b,k]*W[k,n] ----------------
__global__ __launch_bounds__(256) void gemm16_partial(
    const float* __restrict__ A, const float* __restrict__ W, float* __restrict__ P)
{
  int n = blockIdx.x * 256 + threadIdx.x;
  int k0 = blockIdx.y * KCH;
  float acc[B_];
#pragma unroll
  for (int b = 0; b < B_; b++) acc[b] = 0.f;
  const float* Wp = W + (size_t)k0 * DM_ + n;
  const float* Ap = A + k0;
#pragma unroll 8
  for (int kk = 0; kk < KCH; kk++) {
    float w = Wp[(size_t)kk * DM_];
#pragma unroll
    for (int b = 0; b < B_; b++) acc[b] += Ap[b * DM_ + kk] * w;
  }
  float* Pp = P + ((size_t)blockIdx.y * B_) * DM_ + n;
#pragma unroll
  for (int b = 0; b < B_; b++) Pp[(size_t)b * DM_] = acc[b];
}

// ---------------- GEMM stage 2: C[b,n] = bias[n] + sum_ky P[ky][b][n] ----------------
__global__ __launch_bounds__(256) void gemm16_reduce(
    const float* __restrict__ P, const float* __restrict__ bias, float* __restrict__ C)
{
  int i = blockIdx.x * 256 + threadIdx.x;   // over 16*4096
  int b = i >> 12, n = i & (DM_ - 1);
  float s = bias[n];
#pragma unroll
  for (int ky = 0; ky < SPLITK; ky++) s += P[(size_t)(ky * B_ + b) * DM_ + n];
  C[i] = s;
}

// ---------------- landmarks + scores + top-16 + chunk weights + GQA union ----------------
// grid: B*HKV blocks, 1024 threads (16 waves)
__global__ __launch_bounds__(1024) void lmk_topk_kernel(
    const float* __restrict__ q_raw, const float* __restrict__ k_cache,
    const float* __restrict__ lse_swa, const float* __restrict__ qn_w,
    const float* __restrict__ lmkn_w, const int* __restrict__ seq_lens,
    float* __restrict__ q_norm, float* __restrict__ swa_w,
    int* __restrict__ ulist, float* __restrict__ uw, int* __restrict__ ucount)
{
  int blk = blockIdx.x;
  int b = blk / HKV_, kv = blk % HKV_;
  int tid = threadIdx.x;
  int w = tid >> 6, lane = tid & 63;
  int d0 = lane * 2;

  __shared__ float qs[G_][HD_];
  __shared__ float sS[G_][NC_];
  __shared__ float hw[NC_][G_];   // per-chunk weight of each head in group
  __shared__ int hsel[NC_];       // selected-by-any-head flag

  if (tid < NC_) {
    hsel[tid] = 0;
    hw[tid][0] = 0.f; hw[tid][1] = 0.f; hw[tid][2] = 0.f; hw[tid][3] = 0.f;
  }

  const float scale = 0.088388347648318447f;  // 1/sqrt(128)
  float lw0 = lmkn_w[d0], lw1 = lmkn_w[d0 + 1];

  // phase 1: each wave normalizes 4 landmarks (c = w + 16j); waves 0-3 also q-RMSNorm
  float l0[4], l1[4];
#pragma unroll
  for (int j = 0; j < 4; j++) {
    int c = w + 16 * j;
    const float2* kp = (const float2*)(k_cache + (((size_t)b * T_ + c * CHUNK_) * HKV_ + kv) * HD_);
    float2 v = kp[lane];
    float ss = v.x * v.x + v.y * v.y;
#pragma unroll
    for (int off = 1; off < 64; off <<= 1) ss += __shfl_xor(ss, off);
    float rs = rsqrtf(ss * (1.0f / HD_) + EPS_);
    l0[j] = v.x * rs * lw0;
    l1[j] = v.y * rs * lw1;
  }
  if (w < G_) {
    int qh = kv * G_ + w;
    const float* qp = q_raw + ((size_t)b * HQ_ + qh) * HD_;
    float v0 = qp[d0], v1 = qp[d0 + 1];
    float ss = v0 * v0 + v1 * v1;
#pragma unroll
    for (int off = 1; off < 64; off <<= 1) ss += __shfl_xor(ss, off);
    float rs = rsqrtf(ss * (1.0f / HD_) + EPS_);
    float n0 = v0 * rs * qn_w[d0], n1 = v1 * rs * qn_w[d0 + 1];
    qs[w][d0] = n0; qs[w][d0 + 1] = n1;
    float* qo = q_norm + ((size_t)b * HQ_ + qh) * HD_;
    qo[d0] = n0; qo[d0 + 1] = n1;
  }
  __syncthreads();

  // phase 2: dots vs the 4 q heads
#pragma unroll
  for (int j = 0; j < 4; j++) {
    int c = w + 16 * j;
#pragma unroll
    for (int gi = 0; gi < G_; gi++) {
      float p = l0[j] * qs[gi][d0] + l1[j] * qs[gi][d0 + 1];
#pragma unroll
      for (int off = 1; off < 64; off <<= 1) p += __shfl_xor(p, off);
      if (lane == 0) sS[gi][c] = p * scale;
    }
  }
  __syncthreads();

  // phase 3: validity + top-16 + softmax([scores, lse]); waves 0-3, wave w = head w
  if (w < G_) {
    int qh = kv * G_ + w;
    int sl = seq_lens[b];
    int cs = lane * CHUNK_;
    float s = sS[w][lane];
    bool valid = (cs + CHUNK_ <= sl) && (cs < sl - WINDOW_);
    if (!valid) s = -1e9f;

    float topv[TOPK_]; int topi[TOPK_];
    float cur = s;
    for (int j = 0; j < TOPK_; j++) {
      float v = cur; int ix = lane;
#pragma unroll
      for (int off = 1; off < 64; off <<= 1) {
        float ov = __shfl_xor(v, off);
        int oi = __shfl_xor(ix, off);
        if (ov > v || (ov == v && oi < ix)) { v = ov; ix = oi; }
      }
      topv[j] = v; topi[j] = ix;
      if (lane == ix) cur = -INFINITY;
    }

    float lse = lse_swa[b * HQ_ + qh];
    float m = lse;
#pragma unroll
    for (int j = 0; j < TOPK_; j++) m = fmaxf(m, topv[j]);
    float sum = expf(lse - m);
    float e[TOPK_];
#pragma unroll
    for (int j = 0; j < TOPK_; j++) { e[j] = expf(topv[j] - m); sum += e[j]; }
    float inv = 1.0f / sum;
    if (lane == 0) {
      swa_w[b * HQ_ + qh] = expf(lse - m) * inv;
#pragma unroll
      for (int j = 0; j < TOPK_; j++) {
        hw[topi[j]][w] = e[j] * inv;   // distinct column per head, no race
        hsel[topi[j]] = 1;             // benign same-value race across heads
      }
    }
  }
  __syncthreads();

  // phase 4: compact the union of selected chunks (wave 0)
  if (tid < NC_) {
    int sel = hsel[tid];
    unsigned long long mball = __ballot(sel != 0);
    int slot = (int)__popcll(mball & ((1ull << tid) - 1ull));
    if (sel) {
      int base = blk * NC_ + slot;
      ulist[base] = tid;
      uw[base * G_ + 0] = hw[tid][0];
      uw[base * G_ + 1] = hw[tid][1];
      uw[base * G_ + 2] = hw[tid][2];
      uw[base * G_ + 3] = hw[tid][3];
    }
    if (tid == 0) ucount[blk] = (int)__popcll(mball);
  }
}

// ---------------- SWA branch initializes the output accumulator ----------------
// grid: B*HQ*HD/256 = 256 blocks
__global__ __launch_bounds__(256) void init_swa(
    const float* __restrict__ q_norm, const float* __restrict__ swa_w, float* __restrict__ o_acc)
{
  int i = blockIdx.x * 256 + threadIdx.x;
  o_acc[i] = q_norm[i] * swa_w[i >> 7];
}

// ---------------- per-unique-chunk attention for the whole GQA group ----------------
// grid: B*HKV*NC = 8192 blocks (blocks with slot >= ucount exit), 256 threads
__global__ __launch_bounds__(256) void attn_union(
    const float* __restrict__ q_norm, const float* __restrict__ k_cache,
    const float* __restrict__ v_cache, const int* __restrict__ ulist,
    const float* __restrict__ uw, const int* __restrict__ ucount,
    float* __restrict__ o_acc)
{
  int blk = blockIdx.x;
  int u = blk & (NC_ - 1);
  int bk = blk >> 6;                 // b*HKV + kv
  if (u >= ucount[bk]) return;
  int b = bk >> 3, kv = bk & (HKV_ - 1);
  int tid = threadIdx.x;

  __shared__ __align__(16) float qs[G_][HD_];
  __shared__ __align__(16) float4 pS[CHUNK_];          // [token] -> 4 head scores
  __shared__ __align__(16) float Vs[CHUNK_][HD_];
  __shared__ __align__(16) float accS[G_][HD_];

  int base = bk * NC_ + u;
  int c = ulist[base];
  float w0 = uw[base * G_ + 0], w1 = uw[base * G_ + 1];
  float w2 = uw[base * G_ + 2], w3 = uw[base * G_ + 3];

  int tok0 = c * CHUNK_;
  const float* Kbase = k_cache + (((size_t)b * T_ + tok0) * HKV_ + kv) * HD_;
  const float* Vbase = v_cache + (((size_t)b * T_ + tok0) * HKV_ + kv) * HD_;
  const int rowstride = HKV_ * HD_;   // 1024 floats between tokens

  // load the group's 4 q heads (512 floats) with 256 threads
  {
    const float* qbase = q_norm + ((size_t)(b * HQ_ + kv * G_)) * HD_;
    float2 v = ((const float2*)qbase)[tid];
    ((float2*)&qs[0][0])[tid] = v;
  }

  // prefetch V chunk into registers (in flight during score phase)
  float4 vreg[8];
#pragma unroll
  for (int i = 0; i < 8; i++) {
    int f = i * 256 + tid;          // float4 index in [64 x 32]
    int tok = f >> 5, d4 = f & 31;
    vreg[i] = *(const float4*)(Vbase + (size_t)tok * rowstride + d4 * 4);
  }
  __syncthreads();  // qs ready

  // scores: token t (64) x dim-quarter q4 (4), all 4 heads per thread
  {
    int t = tid >> 2, q4 = tid & 3;
    const float4* krow = (const float4*)(Kbase + (size_t)t * rowstride);
    float p0 = 0.f, p1 = 0.f, p2 = 0.f, p3 = 0.f;
#pragma unroll
    for (int i = 0; i < 8; i++) {
      float4 k4 = krow[q4 * 8 + i];
      float4 qa = ((const float4*)qs[0])[q4 * 8 + i];
      float4 qb = ((const float4*)qs[1])[q4 * 8 + i];
      float4 qc = ((const float4*)qs[2])[q4 * 8 + i];
      float4 qd = ((const float4*)qs[3])[q4 * 8 + i];
      p0 += k4.x * qa.x + k4.y * qa.y + k4.z * qa.z + k4.w * qa.w;
      p1 += k4.x * qb.x + k4.y * qb.y + k4.z * qb.z + k4.w * qb.w;
      p2 += k4.x * qc.x + k4.y * qc.y + k4.z * qc.z + k4.w * qc.w;
      p3 += k4.x * qd.x + k4.y * qd.y + k4.z * qd.z + k4.w * qd.w;
    }
    // reduce across the 4-lane q4 group
    p0 += __shfl_xor(p0, 1); p0 += __shfl_xor(p0, 2);
    p1 += __shfl_xor(p1, 1); p1 += __shfl_xor(p1, 2);
    p2 += __shfl_xor(p2, 1); p2 += __shfl_xor(p2, 2);
    p3 += __shfl_xor(p3, 1); p3 += __shfl_xor(p3, 2);
    float sel = (q4 == 0) ? p0 : (q4 == 1) ? p1 : (q4 == 2) ? p2 : p3;
    ((float*)pS)[t * 4 + q4] = sel * 0.088388347648318447f;
  }
  // V registers -> LDS
#pragma unroll
  for (int i = 0; i < 8; i++) {
    int f = i * 256 + tid;
    int tok = f >> 5, d4 = f & 31;
    *(float4*)&Vs[tok][d4 * 4] = vreg[i];
  }
  __syncthreads();

  // per-head softmax over 64 tokens; wave g = head g (chunks are fully valid)
  {
    int w = tid >> 6, lane = tid & 63;
    if (w < G_) {
      float* pf = (float*)pS;
      float s = pf[lane * 4 + w];
      float m = s;
#pragma unroll
      for (int off = 1; off < 64; off <<= 1) m = fmaxf(m, __shfl_xor(m, off));
      float e2 = expf(s - m);
      float sum = e2;
#pragma unroll
      for (int off = 1; off < 64; off <<= 1) sum += __shfl_xor(sum, off);
      pf[lane * 4 + w] = e2 / sum;
    }
  }
  __syncthreads();

  // PV for all 4 heads: dim d (128) x token-half tp (2)
  {
    int d = tid & 127, tp = tid >> 7;
    float a0 = 0.f, a1 = 0.f, a2 = 0.f, a3 = 0.f;
#pragma unroll
    for (int tt = 0; tt < 32; tt++) {
      int tok = tp * 32 + tt;
      float v = Vs[tok][d];
      float4 p = pS[tok];
      a0 += p.x * v; a1 += p.y * v; a2 += p.z * v; a3 += p.w * v;
    }
    if (tp) {
      accS[0][d] = a0; accS[1][d] = a1; accS[2][d] = a2; accS[3][d] = a3;
    }
    __syncthreads();
    if (!tp) {
      float* op = o_acc + ((size_t)(b * HQ_ + kv * G_)) * HD_ + d;
      if (w0 > 0.f) atomicAdd(op,            w0 * (a0 + accS[0][d]));
      if (w1 > 0.f) atomicAdd(op + HD_,      w1 * (a1 + accS[1][d]));
      if (w2 > 0.f) atomicAdd(op + 2 * HD_,  w2 * (a2 + accS[2][d]));
      if (w3 > 0.f) atomicAdd(op + 3 * HD_,  w3 * (a3 + accS[3][d]));
    }
  }
}

extern "C" void kernel_launch(void* const* d_in, const int* in_sizes, int n_in,
                              void* d_out, int out_size, void* d_ws, size_t ws_size,
                              hipStream_t stream)
{
  const float* hidden  = (const float*)d_in[0];
  const float* k_cache = (const float*)d_in[1];
  const float* v_cache = (const float*)d_in[2];
  const float* lse_swa = (const float*)d_in[3];
  const float* Wq      = (const float*)d_in[4];
  const float* bq      = (const float*)d_in[5];
  const float* Wo      = (const float*)d_in[6];
  const float* bo      = (const float*)d_in[7];
  const float* qn_w    = (const float*)d_in[8];
  const float* lmkn_w  = (const float*)d_in[9];
  const int*   seq_lens = (const int*)d_in[10];
  float* out = (float*)d_out;

  float* part1  = (float*)d_ws;                            // 32*16*4096 = 2M floats
  float* q_raw  = part1 + (size_t)SPLITK * B_ * DM_;       // 16*4096
  float* q_norm = q_raw + (size_t)B_ * DM_;                // 16*4096
  float* o_acc  = q_norm + (size_t)B_ * DM_;               // 16*4096
  float* swa_w  = o_acc + (size_t)B_ * DM_;                // 16*32
  float* uw     = swa_w + B_ * HQ_;                        // 16*8*64*4
  int*   ulist  = (int*)(uw + (size_t)B_ * HKV_ * NC_ * G_);  // 16*8*64
  int*   ucount = ulist + B_ * HKV_ * NC_;                 // 16*8

  dim3 gg(DM_ / 256, SPLITK);
  gemm16_partial<<<gg, 256, 0, stream>>>(hidden, Wq, part1);
  gemm16_reduce<<<B_ * DM_ / 256, 256, 0, stream>>>(part1, bq, q_raw);
  lmk_topk_kernel<<<B_ * HKV_, 1024, 0, stream>>>(q_raw, k_cache, lse_swa, qn_w,
                                                  lmkn_w, seq_lens, q_norm, swa_w,
                                                  ulist, uw, ucount);
  init_swa<<<B_ * HQ_ * HD_ / 256, 256, 0, stream>>>(q_norm, swa_w, o_acc);
  attn_union<<<B_ * HKV_ * NC_, 256, 0, stream>>>(q_norm, k_cache, v_cache,
                                                  ulist, uw, ucount, o_acc);
  gemm16_partial<<<gg, 256, 0, stream>>>(o_acc, Wo, part1);
  gemm16_reduce<<<B_ * DM_ / 256, 256, 0, stream>>>(part1, bo, out);
}